// Round 20
// baseline (128.121 us; speedup 1.0000x reference)
//
#include <hip/hip_runtime.h>

// NormEMAVectorQuantizer on MI355X (gfx950)
// N=8192 tokens, C=32, K=8192 codes, B=32, H*W=256.
// R20: THREE dispatches. k_prep deleted — k_max computes its block's token
// norms inline (bf16 into a reused LDS buffer, 80B padded rows), then stages
// emb chunk y fp32->bf16 into the SAME buffer (union -> 21.5KB LDS, 4
// blocks/CU), then the proven MFMA sweep -> pmax. y==0 blocks also write
// fp32 zn, zero packed, zero loss. k_pick = R19's threshold-gated exact
// fp32 rescore (no MFMA, uses zn/emb only). k_final = R17's 256-block fused
// epilogue. Certificate: bf16 dot err <= 2*2^-9 = 0.0078 < eps=0.01 for
// unit rows -> every code that can be the fp32 argmax (incl. all ties) is
// exact-rescored in fp32; (8191-code) key = numpy lowest-index tie-break.
//
// Outputs (float32, concatenated):
//   [0 .. 262144)        z_q_out [B,C,H,W]
//   [262144]             loss (scalar)
//   [262145 .. 270337)   token_ids [B,H,W] as float
//   [270337 .. 532481)   new_embedding [K,C]
//   [532481 .. 540673)   new_cluster_sizes [K]

#define NTOK   8192
#define NCODE  8192
#define CDIM   32
#define HW     256
#define DECAYF 0.99f
#define EPSF   0.01f

#define OUT_ZQ   0
#define OUT_LOSS 262144
#define OUT_IDS  262145
#define OUT_EMB  270337
#define OUT_CS   532481

// workspace byte offsets
#define WS_ZN     0u        // zn row-major [N,C] f32   = 1048576
#define WS_PMAX   1048576u  // f32 [32][N]              = 1048576
#define WS_PACK   2097152u  // u64 [N]                  = 65536   (end 2162688)

#define CHUNK  256
#define NCHUNK (NCODE / CHUNK)  // 32
#define TILES  (CHUNK / 16)     // 16

typedef __attribute__((ext_vector_type(8))) short bf16x8;
typedef __attribute__((ext_vector_type(4))) float f32x4;

__device__ inline unsigned short f2bf(float x) {
    unsigned u = __float_as_uint(x);
    return (unsigned short)((u + 0x7FFFu + ((u >> 16) & 1u)) >> 16);
}
__device__ inline unsigned fmap(float s) {   // monotonic f32 -> u32
    unsigned u = __float_as_uint(s);
    return (u & 0x80000000u) ? ~u : (u | 0x80000000u);
}
__device__ inline float4 pack8bf(float4 p, float4 q) {  // 8 f32 -> 8 bf16
    unsigned w0 = (unsigned)f2bf(p.x) | ((unsigned)f2bf(p.y) << 16);
    unsigned w1 = (unsigned)f2bf(p.z) | ((unsigned)f2bf(p.w) << 16);
    unsigned w2 = (unsigned)f2bf(q.x) | ((unsigned)f2bf(q.y) << 16);
    unsigned w3 = (unsigned)f2bf(q.z) | ((unsigned)f2bf(q.w) << 16);
    float4 o;
    o.x = __uint_as_float(w0); o.y = __uint_as_float(w1);
    o.z = __uint_as_float(w2); o.w = __uint_as_float(w3);
    return o;
}

// -------- Kernel A: inline-prep MFMA sweep -> pmax[chunk][tok] -----------------
// grid (32 token-groups, 32 chunks). One reused LDS buffer (80B rows, 16B
// aligned, b128 reads run at the optimal 8-phase floor):
//   phase 1: block's 256 token norms -> bf16 rows -> A-frags (regs)
//   phase 2: emb chunk y fp32->bf16 staged into same buffer
//   phase 3: 16x16x32 MFMA running-max sweep
// y==0 blocks also write fp32 zn, zero packed, zero out[LOSS].
__global__ __launch_bounds__(256) void k_max(const float* __restrict__ z,
                                             const float* __restrict__ emb,
                                             float* __restrict__ zn,
                                             float* __restrict__ pmax,
                                             unsigned long long* __restrict__ packed,
                                             float* __restrict__ out) {
    __shared__ float4 lbuf[CHUNK * 5];            // 20 KiB, 80B rows (reused)
    __shared__ float lmax[256];
    int x = blockIdx.x, y = blockIdx.y, t = threadIdx.x;
    int tok0 = x * 256;

    // ---- phase 1: token norm -> bf16 LDS row (+ zn/packed/loss when y==0) ----
    {
        int n = tok0 + t;
        int b = n >> 8, hw = n & 255;
        const float* zp = z + (size_t)b * (CDIM * HW) + hw;
        float v[CDIM];
        float ss = 0.f;
#pragma unroll
        for (int c = 0; c < CDIM; ++c) {
            float tv = zp[c * HW];                // coalesced per c
            v[c] = tv;
            ss += tv * tv;
        }
        float d = fmaxf(sqrtf(ss), 1e-12f);
#pragma unroll
        for (int c = 0; c < CDIM; ++c) v[c] /= d;
        if (y == 0) {
            float* o = zn + (size_t)n * CDIM;
#pragma unroll
            for (int c = 0; c < CDIM; ++c) o[c] = v[c];
            packed[n] = 0ull;
            if (x == 0 && t == 0) out[OUT_LOSS] = 0.f;
        }
#pragma unroll
        for (int s = 0; s < 4; ++s) {             // 4x16B stores, row stride 80B
            float4 p = {v[8 * s + 0], v[8 * s + 1], v[8 * s + 2], v[8 * s + 3]};
            float4 q = {v[8 * s + 4], v[8 * s + 5], v[8 * s + 6], v[8 * s + 7]};
            lbuf[t * 5 + s] = pack8bf(p, q);
        }
    }
    __syncthreads();

    int wave = t >> 6, lane = t & 63;
    int col = lane & 15, quad = lane >> 4;

    bf16x8 a[4];                                  // 4 frags = 64 tokens
    {
        const bf16x8* la = (const bf16x8*)lbuf;   // 16B units, row stride 5
#pragma unroll
        for (int f = 0; f < 4; ++f)
            a[f] = la[(wave * 64 + f * 16 + col) * 5 + quad];
    }
    __syncthreads();                              // all reads done; reuse lbuf

    // ---- phase 2: stage emb chunk y (fp32 -> bf16, padded rows) ----
    {
        int kbase = y * CHUNK;
        const float4* src = (const float4*)(emb + (size_t)kbase * CDIM);
#pragma unroll
        for (int j = 0; j < 4; ++j) {
            int u = t + j * 256;                  // 16B bf16 unit within chunk
            float4 p = src[u * 2], q = src[u * 2 + 1];
            lbuf[(u >> 2) * 5 + (u & 3)] = pack8bf(p, q);
        }
    }
    __syncthreads();

    // ---- phase 3: MFMA running-max sweep ----
    const bf16x8* bl = (const bf16x8*)lbuf;
    const f32x4 zero4 = {0.f, 0.f, 0.f, 0.f};
    float m[4][4];
#pragma unroll
    for (int f = 0; f < 4; ++f)
#pragma unroll
        for (int r = 0; r < 4; ++r) m[f][r] = -1e30f;

    for (int tt = 0; tt < TILES; ++tt) {
        bf16x8 b = bl[(tt * 16 + col) * 5 + quad];
#pragma unroll
        for (int f = 0; f < 4; ++f) {
            f32x4 d = __builtin_amdgcn_mfma_f32_16x16x32_bf16(a[f], b, zero4, 0, 0, 0);
#pragma unroll
            for (int r = 0; r < 4; ++r) m[f][r] = fmaxf(m[f][r], d[r]);
        }
    }
#pragma unroll
    for (int f = 0; f < 4; ++f)
#pragma unroll
        for (int r = 0; r < 4; ++r) {
            float v = m[f][r];
#pragma unroll
            for (int s = 1; s < 16; s <<= 1) v = fmaxf(v, __shfl_xor(v, s));
            if (col == 0) lmax[wave * 64 + f * 16 + quad * 4 + r] = v;
        }
    __syncthreads();
    pmax[(size_t)y * NTOK + tok0 + t] = lmax[t];
}

// -------- Kernel B: threshold-gated exact fp32 rescore (NO MFMA) ---------------
// Block (x,y): thread t owns code y*256+t (emb row in registers). Tokens of
// group x with pmax[y][tok] >= gmax-eps (~8.4/block) get ALL 256 codes
// exact-rescored; wave-reduced key -> atomicMax packed[tok].
__global__ __launch_bounds__(256, 4) void k_pick(const float* __restrict__ zn,
                                                 const float* __restrict__ emb,
                                                 const float* __restrict__ pmax,
                                                 unsigned long long* __restrict__ packed) {
    __shared__ int qlist[256];
    __shared__ int qcnt;
    int t = threadIdx.x, lane = t & 63;
    int x = blockIdx.x, y = blockIdx.y;
    int code = y * CHUNK + t;

    if (t == 0) qcnt = 0;

    // emb row -> registers (sequential 32KB/block stream, reused every iter)
    const float4* ef = (const float4*)(emb + (size_t)code * CDIM);
    float4 e0 = ef[0], e1 = ef[1], e2 = ef[2], e3 = ef[3];
    float4 e4 = ef[4], e5 = ef[5], e6 = ef[6], e7 = ef[7];

    // per-token gmax + this chunk's qualification
    int tok = x * 256 + t;
    float mx = -1e30f, pmy = -1e30f;
#pragma unroll
    for (int ch = 0; ch < NCHUNK; ++ch) {         // coalesced
        float p = pmax[(size_t)ch * NTOK + tok];
        if (ch == y) pmy = p;
        mx = fmaxf(mx, p);
    }
    __syncthreads();                              // qcnt=0 visible
    if (pmy >= mx - EPSF) qlist[atomicAdd(&qcnt, 1)] = t;
    __syncthreads();
    int nq = qcnt;

    for (int i = 0; i < nq; ++i) {
        int tl = __builtin_amdgcn_readfirstlane(qlist[i]);
        int n = x * 256 + tl;
        const float* zp = zn + (size_t)n * CDIM;  // uniform -> scalar loads
        float a0 = zp[0] * e0.x, a1 = zp[1] * e0.y;
        float a2 = zp[2] * e0.z, a3 = zp[3] * e0.w;
        a0 = __builtin_fmaf(zp[4], e1.x, a0);  a1 = __builtin_fmaf(zp[5], e1.y, a1);
        a2 = __builtin_fmaf(zp[6], e1.z, a2);  a3 = __builtin_fmaf(zp[7], e1.w, a3);
        a0 = __builtin_fmaf(zp[8], e2.x, a0);  a1 = __builtin_fmaf(zp[9], e2.y, a1);
        a2 = __builtin_fmaf(zp[10], e2.z, a2); a3 = __builtin_fmaf(zp[11], e2.w, a3);
        a0 = __builtin_fmaf(zp[12], e3.x, a0); a1 = __builtin_fmaf(zp[13], e3.y, a1);
        a2 = __builtin_fmaf(zp[14], e3.z, a2); a3 = __builtin_fmaf(zp[15], e3.w, a3);
        a0 = __builtin_fmaf(zp[16], e4.x, a0); a1 = __builtin_fmaf(zp[17], e4.y, a1);
        a2 = __builtin_fmaf(zp[18], e4.z, a2); a3 = __builtin_fmaf(zp[19], e4.w, a3);
        a0 = __builtin_fmaf(zp[20], e5.x, a0); a1 = __builtin_fmaf(zp[21], e5.y, a1);
        a2 = __builtin_fmaf(zp[22], e5.z, a2); a3 = __builtin_fmaf(zp[23], e5.w, a3);
        a0 = __builtin_fmaf(zp[24], e6.x, a0); a1 = __builtin_fmaf(zp[25], e6.y, a1);
        a2 = __builtin_fmaf(zp[26], e6.z, a2); a3 = __builtin_fmaf(zp[27], e6.w, a3);
        a0 = __builtin_fmaf(zp[28], e7.x, a0); a1 = __builtin_fmaf(zp[29], e7.y, a1);
        a2 = __builtin_fmaf(zp[30], e7.z, a2); a3 = __builtin_fmaf(zp[31], e7.w, a3);
        float s = (a0 + a1) + (a2 + a3);
        unsigned long long key = ((unsigned long long)fmap(s) << 13) |
                                 (unsigned long long)(8191 - code);
#pragma unroll
        for (int sh = 1; sh < 64; sh <<= 1) {
            unsigned long long o = __shfl_xor(key, sh);
            if (o > key) key = o;
        }
        if (lane == 0) atomicMax(packed + n, key);  // 4/token, 8192 addrs
    }
}

// -------- Kernel C: fused epilogue, 256 blocks ---------------------------------
// Block b: (a) ids/z_q/loss for tokens 32b..32b+31; (b) bins+esum for codes
// 32b..32b+31 by scanning all packed (coalesced, ~8 hits/wave), then EMA.
__global__ __launch_bounds__(256) void k_final(const unsigned long long* __restrict__ packed,
                                               const float* __restrict__ zn,
                                               const float* __restrict__ emb,
                                               const float* __restrict__ cs,
                                               float* __restrict__ out) {
    __shared__ float lesum[32][32];               // 4 KiB
    __shared__ int lbins[32];
    __shared__ int lsid[32];
    __shared__ float ls4[4];

    int blk = blockIdx.x, t = threadIdx.x;
    int wave = t >> 6, lane = t & 63;
    int tok0 = blk * 32, kbase = blk * 32;

    if (t < 32) lbins[t] = 0;
#pragma unroll
    for (int i = 0; i < 4; ++i) {
        int idx = i * 256 + t;
        lesum[idx >> 5][idx & 31] = 0.f;
    }
    if (t < 32) {                                 // unpack ids for our tokens
        int n = tok0 + t;
        int id = 8191 - (int)(packed[n] & 8191ull);
        lsid[t] = id;
        out[OUT_IDS + n] = (float)id;
    }
    __syncthreads();

    // ---- z_q gather + transpose-out + loss partial ----
    float s = 0.f;
#pragma unroll
    for (int i = 0; i < 4; ++i) {
        int idx = i * 256 + t;
        int tl = idx >> 5, c = idx & 31;
        int n = tok0 + tl;
        int id = lsid[tl];
        float ev = emb[(size_t)id * CDIM + c];    // <=32 rows, L1/L2
        float zv = zn[(size_t)n * CDIM + c];      // coalesced row reads
        int b = n >> 8, hw = n & 255;
        out[OUT_ZQ + ((size_t)b * CDIM + c) * HW + hw] = ev;
        float dd = ev - zv;
        s += dd * dd;
    }
#pragma unroll
    for (int off = 32; off > 0; off >>= 1) s += __shfl_down(s, off);
    if (lane == 0) ls4[wave] = s;
    __syncthreads();
    if (t == 0)
        atomicAdd(out + OUT_LOSS,
                  (ls4[0] + ls4[1] + ls4[2] + ls4[3]) * (1.0f / 262144.0f));

    // ---- bins + esum: scan all tokens for hits in our code window ----
    for (int i = 0; i < 32; ++i) {
        int n = i * 256 + t;                      // coalesced
        int id = 8191 - (int)(packed[n] & 8191ull);
        unsigned kl = (unsigned)(id - kbase);
        if (kl < 32u) {                           // ~8 hits per wave total
            atomicAdd(&lbins[kl], 1);
            const float* zp = zn + (size_t)n * CDIM;
#pragma unroll
            for (int c = 0; c < CDIM; ++c)
                atomicAdd(&lesum[kl][c], zp[c]);
        }
    }
    __syncthreads();

    // ---- EMA update + renormalize for our 32 codes ----
#pragma unroll
    for (int i = 0; i < 4; ++i) {
        int idx = i * 256 + t;
        int kl = idx >> 5, c = idx & 31;
        int k = kbase + kl;
        int bi = lbins[kl];
        float bf = (float)bi;
        bool zero = (bi == 0);
        float tv = lesum[kl][c] / (zero ? 1.0f : bf);
        float ss = tv * tv;
#pragma unroll
        for (int sh = 1; sh < 32; sh <<= 1) ss += __shfl_xor(ss, sh);
        float d = fmaxf(sqrtf(ss), 1e-12f);
        float ew = emb[(size_t)k * CDIM + c];
        float en = zero ? ew : (tv / d);
        float w = ew * DECAYF + (1.0f - DECAYF) * en;
        float ss2 = w * w;
#pragma unroll
        for (int sh = 1; sh < 32; sh <<= 1) ss2 += __shfl_xor(ss2, sh);
        float d2 = fmaxf(sqrtf(ss2), 1e-12f);
        out[OUT_EMB + (size_t)k * CDIM + c] = w / d2;
        if (c == 0) out[OUT_CS + k] = cs[k] * DECAYF + (1.0f - DECAYF) * bf;
    }
}

extern "C" void kernel_launch(void* const* d_in, const int* in_sizes, int n_in,
                              void* d_out, int out_size, void* d_ws, size_t ws_size,
                              hipStream_t stream) {
    const float* z   = (const float*)d_in[0];   // [32,32,16,16]
    const float* emb = (const float*)d_in[1];   // [8192,32]
    const float* cs  = (const float*)d_in[2];   // [8192]
    float* out = (float*)d_out;
    char* ws = (char*)d_ws;

    float* zn                  = (float*)(ws + WS_ZN);
    float* pmax                = (float*)(ws + WS_PMAX);
    unsigned long long* packed = (unsigned long long*)(ws + WS_PACK);

    k_max<<<dim3(NTOK / 256, NCHUNK), 256, 0, stream>>>(z, emb, zn, pmax, packed, out);
    k_pick<<<dim3(NTOK / 256, NCHUNK), 256, 0, stream>>>(zn, emb, pmax, packed);
    k_final<<<dim3(256), 256, 0, stream>>>(packed, zn, emb, cs, out);
}

// Round 21
// 120.567 us; speedup vs baseline: 1.0627x; 1.0627x over previous
//
#include <hip/hip_runtime.h>

// NormEMAVectorQuantizer on MI355X (gfx950)
// N=8192 tokens, C=32, K=8192 codes, B=32, H*W=256.
// R21 = R17 verbatim (measured best: 119.8us). R18 (k_final regrid), R19
// (no-MFMA k_pick), R20 (3-dispatch fusion) all regressed to 123-128us:
// every owned kernel is <15us; total is dominated by the harness's 268MB
// ws re-poison fill (~42us in-replay) + d_out memset + 4 launch gaps.
// Pipeline: prep+zero | k_max | k_pick | k_final  (4 dispatches).
// Certificate: bf16 dot err <= 2*2^-9 = 0.0078 < eps=0.01 for unit rows ->
// every code that can be the fp32 argmax (incl. all ties) is exact-rescored
// in fp32; (8191-code) key = numpy lowest-index tie-break.
//
// Outputs (float32, concatenated):
//   [0 .. 262144)        z_q_out [B,C,H,W]
//   [262144]             loss (scalar)
//   [262145 .. 270337)   token_ids [B,H,W] as float
//   [270337 .. 532481)   new_embedding [K,C]
//   [532481 .. 540673)   new_cluster_sizes [K]

#define NTOK   8192
#define NCODE  8192
#define CDIM   32
#define HW     256
#define DECAYF 0.99f
#define EPSF   0.01f

#define OUT_ZQ   0
#define OUT_LOSS 262144
#define OUT_IDS  262145
#define OUT_EMB  270337
#define OUT_CS   532481

// workspace byte offsets
#define WS_ZN     0u        // zn row-major [N,C] f32   = 1048576
#define WS_ZNBF   1048576u  // bf16 [N,C]               = 524288
#define WS_EBF    1572864u  // bf16 [K,C]               = 524288
#define WS_PMAX   2097152u  // f32 [32][N]              = 1048576
#define WS_PACK   3145728u  // u64 [N]                  = 65536   (end 3211264)

#define CHUNK  256
#define NCHUNK (NCODE / CHUNK)  // 32
#define TILES  (CHUNK / 16)     // 16

typedef __attribute__((ext_vector_type(8))) short bf16x8;
typedef __attribute__((ext_vector_type(4))) float f32x4;

__device__ inline unsigned short f2bf(float x) {
    unsigned u = __float_as_uint(x);
    return (unsigned short)((u + 0x7FFFu + ((u >> 16) & 1u)) >> 16);
}
__device__ inline unsigned fmap(float s) {   // monotonic f32 -> u32
    unsigned u = __float_as_uint(s);
    return (u & 0x80000000u) ? ~u : (u | 0x80000000u);
}

// stage one 256x32 bf16 chunk into LDS with rows padded to 5 float4 units
// (80B): banks cycle 20*row%32 -> max 2-way conflict on read and write.
__device__ inline void stage_chunk(const unsigned short* __restrict__ ebf,
                                   int kbase, float4* lbs5, int t) {
    const float4* src = (const float4*)(ebf + (size_t)kbase * CDIM);
#pragma unroll
    for (int j = 0; j < 4; ++j) {
        int u = t + j * 256;                      // global float4 unit in chunk
        int row = u >> 2, seg = u & 3;
        lbs5[row * 5 + seg] = src[u];
    }
}

// -------- Kernel A: prep (norm + bf16 + emb bf16) + zero packed + zero loss ----
__global__ __launch_bounds__(256) void k_prep(const float* __restrict__ z,
                                              const float* __restrict__ emb,
                                              float* __restrict__ zn,
                                              unsigned short* __restrict__ znbf,
                                              unsigned short* __restrict__ ebf,
                                              unsigned long long* __restrict__ packed,
                                              float* __restrict__ out) {
    int bid = blockIdx.x, t = threadIdx.x;
    if (bid < 32) {                               // token norm -> zn, znbf
        int n = bid * 256 + t;
        int b = n >> 8, hw = n & 255;
        const float* zp = z + (size_t)b * (CDIM * HW) + hw;
        float v[CDIM];
        float ss = 0.f;
#pragma unroll
        for (int c = 0; c < CDIM; ++c) {
            float tv = zp[c * HW];                // coalesced per c
            v[c] = tv;
            ss += tv * tv;
        }
        float d = fmaxf(sqrtf(ss), 1e-12f);
        float* o = zn + (size_t)n * CDIM;
        unsigned short* ob = znbf + (size_t)n * CDIM;
#pragma unroll
        for (int c = 0; c < CDIM; ++c) {
            float tv = v[c] / d;
            o[c] = tv;
            ob[c] = f2bf(tv);
        }
    } else if (bid < 160) {                       // emb -> ebf
        int base = (bid - 32) * 2048 + t * 8;
        const float4* s = (const float4*)(emb + base);
        float4 x4 = s[0], y4 = s[1];
        ushort4 u0 = {f2bf(x4.x), f2bf(x4.y), f2bf(x4.z), f2bf(x4.w)};
        ushort4 u1 = {f2bf(y4.x), f2bf(y4.y), f2bf(y4.z), f2bf(y4.w)};
        *(ushort4*)(ebf + base) = u0;
        *(ushort4*)(ebf + base + 4) = u1;
    } else if (bid < 164) {                       // zero packed
        int base = (bid - 160) * 2048 + t;
#pragma unroll
        for (int j = 0; j < 8; ++j) packed[base + j * 256] = 0ull;
    } else {                                      // bid==164: zero loss slot
        if (t == 0) out[OUT_LOSS] = 0.f;
    }
}

// -------- Kernel B: MFMA sweep -> pmax[chunk][tok] (padded LDS, no conflicts) --
__global__ __launch_bounds__(256) void k_max(const unsigned short* __restrict__ znbf,
                                             const unsigned short* __restrict__ ebf,
                                             float* __restrict__ pmax) {
    __shared__ float4 lbs5[CHUNK * 5];            // 20 KiB, 80B rows
    __shared__ float lmax[256];
    int kbase = blockIdx.y * CHUNK;
    stage_chunk(ebf, kbase, lbs5, threadIdx.x);
    __syncthreads();

    int wave = threadIdx.x >> 6, lane = threadIdx.x & 63;
    int col = lane & 15, quad = lane >> 4;
    int wtok = blockIdx.x * 256 + wave * 64;

    bf16x8 a[4];                                  // 4 frags = 64 tokens
#pragma unroll
    for (int f = 0; f < 4; ++f)
        a[f] = *(const bf16x8*)(znbf + (size_t)(wtok + f * 16 + col) * CDIM + quad * 8);

    const bf16x8* bl = (const bf16x8*)lbs5;       // 16B units, row stride 5
    const f32x4 zero4 = {0.f, 0.f, 0.f, 0.f};
    float m[4][4];
#pragma unroll
    for (int f = 0; f < 4; ++f)
#pragma unroll
        for (int r = 0; r < 4; ++r) m[f][r] = -1e30f;

    for (int t = 0; t < TILES; ++t) {
        bf16x8 b = bl[(t * 16 + col) * 5 + quad];
#pragma unroll
        for (int f = 0; f < 4; ++f) {
            f32x4 d = __builtin_amdgcn_mfma_f32_16x16x32_bf16(a[f], b, zero4, 0, 0, 0);
#pragma unroll
            for (int r = 0; r < 4; ++r) m[f][r] = fmaxf(m[f][r], d[r]);
        }
    }
#pragma unroll
    for (int f = 0; f < 4; ++f)
#pragma unroll
        for (int r = 0; r < 4; ++r) {
            float v = m[f][r];
#pragma unroll
            for (int s = 1; s < 16; s <<= 1) v = fmaxf(v, __shfl_xor(v, s));
            if (col == 0) lmax[wave * 64 + f * 16 + quad * 4 + r] = v;
        }
    __syncthreads();
    pmax[(size_t)blockIdx.y * NTOK + blockIdx.x * 256 + threadIdx.x] = lmax[threadIdx.x];
}

// -------- Kernel C: dense rescan vs gmax-eps + inline exact fp32 rescore -------
__global__ __launch_bounds__(256) void k_pick(const unsigned short* __restrict__ znbf,
                                              const unsigned short* __restrict__ ebf,
                                              const float* __restrict__ zn,
                                              const float* __restrict__ emb,
                                              const float* __restrict__ pmax,
                                              unsigned long long* __restrict__ packed) {
    __shared__ float4 lbs5[CHUNK * 5];            // 20 KiB
    __shared__ float lthr[256];
    int kbase = blockIdx.y * CHUNK;
    stage_chunk(ebf, kbase, lbs5, threadIdx.x);
    {   // per-token global threshold: 32 coalesced loads
        int tok = blockIdx.x * 256 + threadIdx.x;
        float mx = -1e30f;
#pragma unroll
        for (int ch = 0; ch < NCHUNK; ++ch)
            mx = fmaxf(mx, pmax[(size_t)ch * NTOK + tok]);
        lthr[threadIdx.x] = mx - EPSF;
    }
    __syncthreads();

    int wave = threadIdx.x >> 6, lane = threadIdx.x & 63;
    int col = lane & 15, quad = lane >> 4;
    int wtok = blockIdx.x * 256 + wave * 64;

    bf16x8 a[4];
#pragma unroll
    for (int f = 0; f < 4; ++f)
        a[f] = *(const bf16x8*)(znbf + (size_t)(wtok + f * 16 + col) * CDIM + quad * 8);

    float thr[4][4];
#pragma unroll
    for (int f = 0; f < 4; ++f)
#pragma unroll
        for (int r = 0; r < 4; ++r)
            thr[f][r] = lthr[wave * 64 + f * 16 + quad * 4 + r];

    const bf16x8* bl = (const bf16x8*)lbs5;
    const f32x4 zero4 = {0.f, 0.f, 0.f, 0.f};

    for (int t = 0; t < TILES; ++t) {
        bf16x8 b = bl[(t * 16 + col) * 5 + quad];
#pragma unroll
        for (int f = 0; f < 4; ++f) {
            f32x4 d = __builtin_amdgcn_mfma_f32_16x16x32_bf16(a[f], b, zero4, 0, 0, 0);
#pragma unroll
            for (int r = 0; r < 4; ++r) {
                if (d[r] >= thr[f][r]) {          // rare: ~1.05/token total
                    int tok = wtok + f * 16 + quad * 4 + r;
                    int code = kbase + t * 16 + col;
                    const float* zp = zn + (size_t)tok * CDIM;
                    const float* ep = emb + (size_t)code * CDIM;
                    float a0 = 0.f, a1 = 0.f, a2 = 0.f, a3 = 0.f;
#pragma unroll
                    for (int j = 0; j < 8; ++j) {
                        a0 = __builtin_fmaf(zp[4 * j + 0], ep[4 * j + 0], a0);
                        a1 = __builtin_fmaf(zp[4 * j + 1], ep[4 * j + 1], a1);
                        a2 = __builtin_fmaf(zp[4 * j + 2], ep[4 * j + 2], a2);
                        a3 = __builtin_fmaf(zp[4 * j + 3], ep[4 * j + 3], a3);
                    }
                    float s = (a0 + a1) + (a2 + a3);
                    atomicMax(packed + tok, ((unsigned long long)fmap(s) << 13) |
                                            (unsigned long long)(8191 - code));
                }
            }
        }
    }
}

// -------- Kernel D: fused epilogue, 256 blocks ---------------------------------
// Block b: (a) ids/z_q/loss for tokens 32b..32b+31; (b) bins+esum for codes
// 32b..32b+31 by scanning all packed (coalesced, ~8 hits/wave), then EMA.
__global__ __launch_bounds__(256) void k_final(const unsigned long long* __restrict__ packed,
                                               const float* __restrict__ zn,
                                               const float* __restrict__ emb,
                                               const float* __restrict__ cs,
                                               float* __restrict__ out) {
    __shared__ float lesum[32][32];               // 4 KiB
    __shared__ int lbins[32];
    __shared__ int lsid[32];
    __shared__ float ls4[4];

    int blk = blockIdx.x, t = threadIdx.x;
    int wave = t >> 6, lane = t & 63;
    int tok0 = blk * 32, kbase = blk * 32;

    if (t < 32) lbins[t] = 0;
#pragma unroll
    for (int i = 0; i < 4; ++i) {
        int idx = i * 256 + t;
        lesum[idx >> 5][idx & 31] = 0.f;
    }
    if (t < 32) {                                 // unpack ids for our tokens
        int n = tok0 + t;
        int id = 8191 - (int)(packed[n] & 8191ull);
        lsid[t] = id;
        out[OUT_IDS + n] = (float)id;
    }
    __syncthreads();

    // ---- z_q gather + transpose-out + loss partial ----
    float s = 0.f;
#pragma unroll
    for (int i = 0; i < 4; ++i) {
        int idx = i * 256 + t;
        int tl = idx >> 5, c = idx & 31;
        int n = tok0 + tl;
        int id = lsid[tl];
        float ev = emb[(size_t)id * CDIM + c];    // <=32 rows, L1/L2
        float zv = zn[(size_t)n * CDIM + c];      // coalesced row reads
        int b = n >> 8, hw = n & 255;
        out[OUT_ZQ + ((size_t)b * CDIM + c) * HW + hw] = ev;
        float dd = ev - zv;
        s += dd * dd;
    }
#pragma unroll
    for (int off = 32; off > 0; off >>= 1) s += __shfl_down(s, off);
    if (lane == 0) ls4[wave] = s;
    __syncthreads();
    if (t == 0)
        atomicAdd(out + OUT_LOSS,
                  (ls4[0] + ls4[1] + ls4[2] + ls4[3]) * (1.0f / 262144.0f));

    // ---- bins + esum: scan all tokens for hits in our code window ----
    for (int i = 0; i < 32; ++i) {
        int n = i * 256 + t;                      // coalesced
        int id = 8191 - (int)(packed[n] & 8191ull);
        unsigned kl = (unsigned)(id - kbase);
        if (kl < 32u) {                           // ~8 hits per wave total
            atomicAdd(&lbins[kl], 1);
            const float* zp = zn + (size_t)n * CDIM;
#pragma unroll
            for (int c = 0; c < CDIM; ++c)
                atomicAdd(&lesum[kl][c], zp[c]);
        }
    }
    __syncthreads();

    // ---- EMA update + renormalize for our 32 codes ----
#pragma unroll
    for (int i = 0; i < 4; ++i) {
        int idx = i * 256 + t;
        int kl = idx >> 5, c = idx & 31;
        int k = kbase + kl;
        int bi = lbins[kl];
        float bf = (float)bi;
        bool zero = (bi == 0);
        float tv = lesum[kl][c] / (zero ? 1.0f : bf);
        float ss = tv * tv;
#pragma unroll
        for (int sh = 1; sh < 32; sh <<= 1) ss += __shfl_xor(ss, sh);
        float d = fmaxf(sqrtf(ss), 1e-12f);
        float ew = emb[(size_t)k * CDIM + c];
        float en = zero ? ew : (tv / d);
        float w = ew * DECAYF + (1.0f - DECAYF) * en;
        float ss2 = w * w;
#pragma unroll
        for (int sh = 1; sh < 32; sh <<= 1) ss2 += __shfl_xor(ss2, sh);
        float d2 = fmaxf(sqrtf(ss2), 1e-12f);
        out[OUT_EMB + (size_t)k * CDIM + c] = w / d2;
        if (c == 0) out[OUT_CS + k] = cs[k] * DECAYF + (1.0f - DECAYF) * bf;
    }
}

extern "C" void kernel_launch(void* const* d_in, const int* in_sizes, int n_in,
                              void* d_out, int out_size, void* d_ws, size_t ws_size,
                              hipStream_t stream) {
    const float* z   = (const float*)d_in[0];   // [32,32,16,16]
    const float* emb = (const float*)d_in[1];   // [8192,32]
    const float* cs  = (const float*)d_in[2];   // [8192]
    float* out = (float*)d_out;
    char* ws = (char*)d_ws;

    float* zn                  = (float*)(ws + WS_ZN);
    unsigned short* znbf       = (unsigned short*)(ws + WS_ZNBF);
    unsigned short* ebf        = (unsigned short*)(ws + WS_EBF);
    float* pmax                = (float*)(ws + WS_PMAX);
    unsigned long long* packed = (unsigned long long*)(ws + WS_PACK);

    k_prep<<<dim3(165), 256, 0, stream>>>(z, emb, zn, znbf, ebf, packed, out);
    k_max<<<dim3(NTOK / 256, NCHUNK), 256, 0, stream>>>(znbf, ebf, pmax);
    k_pick<<<dim3(NTOK / 256, NCHUNK), 256, 0, stream>>>(znbf, ebf, zn, emb, pmax, packed);
    k_final<<<dim3(256), 256, 0, stream>>>(packed, zn, emb, cs, out);
}